// Round 26
// baseline (58.117 us; speedup 1.0000x reference)
//
#include <hip/hip_runtime.h>
#include <hip/hip_bf16.h>
#include <stdint.h>
#include <math.h>

typedef __attribute__((ext_vector_type(8))) short short8;
typedef __attribute__((ext_vector_type(4))) float f32x4;

#define NTHREADS 256
#define DIM 128
#define NH 16
#define HD 8
#define HIDDEN 344
#define HIDP 352          // HIDDEN padded to multiple of 32 (22 col-tiles)
#define BATCH 4
#define SEQ 2048
#define MROWS (BATCH * SEQ)   // 8192
#define LOG2E 1.4426950408889634f

static __device__ __forceinline__ uint16_t f2bf(float f) {
  union { float f; uint32_t u; } v; v.f = f;
  uint32_t r = v.u + 0x7FFFu + ((v.u >> 16) & 1u);
  return (uint16_t)(r >> 16);
}
// RNE pack: compiler emits v_cvt_pk_bf16_f32
static __device__ __forceinline__ uint32_t pk2(float lo, float hi) {
  union { __hip_bfloat162 b; uint32_t u; } c;
  c.b = __float22bfloat162_rn(make_float2(lo, hi));
  return c.u;
}
// ---- 1-fma exp2 -> bf16 (Schraudolph + 1.5*2^23 magic-add) ----
// SCALAR FMA ONLY (r22 asm NaN; r24 compiler-packed 0.109 absmax).
#define MAGIC_BF 12599163.0f   // 1.5*2^23 + (127 - 0.0436)*2^7
static __device__ __forceinline__ uint32_t pke2(float a, float b) {
  const float ua = fmaf(a, 128.0f, MAGIC_BF);
  const float ub = fmaf(b, 128.0f, MAGIC_BF);
  return __builtin_amdgcn_perm(__builtin_bit_cast(uint32_t, ub),
                               __builtin_bit_cast(uint32_t, ua), 0x05040100u);
}
static __device__ __forceinline__ f32x4 mfma32(short8 a, short8 b, f32x4 c) {
  return __builtin_amdgcn_mfma_f32_16x16x32_bf16(a, b, c, 0, 0, 0);
}

// ------------------------------------------------------------------
// prep: ONLY qkv_t (needed before qkv_gemm). FFN weights are converted
// inside qkv_gemm's prologue (hidden under its latency; they're first
// read two launches later by ffn_kernel -- stream ordering guarantees).
// ------------------------------------------------------------------
__global__ __launch_bounds__(256) void prep_kernel(
    const float* __restrict__ wq,
    const float* __restrict__ wk, const float* __restrict__ wv,
    uint16_t* __restrict__ qkv_t)
{
  const int nt  = gridDim.x * blockDim.x;
  const int tid = blockIdx.x * blockDim.x + threadIdx.x;
  for (int i = tid; i < 384 * 128; i += nt) {
    int n = i >> 7, k = i & 127;
    const float* w = (n < 128) ? wq : ((n < 256) ? wk : wv);
    const float s = (n < 128) ? LOG2E : 1.0f;
    qkv_t[i] = f2bf(w[k * 128 + (n & 127)] * s);
  }
}

// ------------------------------------------------------------------
// Register-streaming QKV GEMM with B-frag software pipeline (r19)
// + FFN-WEIGHT CONVERSION PROLOGUE: 768 blocks x 256 thr = 196,608
// threads; one weight element each (159,744 total: wo_t 16384,
// w1_t/w3_t 49152 each, w2_t 45056). The scattered f32 load/convert/
// store hides under the GEMM's L2-latency stalls.
// ------------------------------------------------------------------
__global__ __launch_bounds__(256, 4) void qkv_gemm(
    const float* __restrict__ Av, const uint16_t* __restrict__ B1t,
    uint16_t* __restrict__ outb,
    uint16_t* __restrict__ kc_o, uint16_t* __restrict__ vt_o,
    const float* __restrict__ wo, const float* __restrict__ w1,
    const float* __restrict__ w3, const float* __restrict__ w2,
    uint16_t* __restrict__ wo_t, uint16_t* __restrict__ w1_t,
    uint16_t* __restrict__ w3_t, uint16_t* __restrict__ w2_t)
{
  const int tid = threadIdx.x;

  // ---- FFN-weight conversion (one element per thread) ----
  {
    const int gtid = (blockIdx.y * gridDim.x + blockIdx.x) * NTHREADS + tid;
    if (gtid < 16384) {                       // wo_t [128][128]
      const int n = gtid >> 7, k = gtid & 127;
      wo_t[gtid] = f2bf(wo[k * 128 + n]);
    } else if (gtid < 65536) {                // w1_t [384][128]
      const int i = gtid - 16384;
      const int n = i >> 7, k = i & 127;
      w1_t[i] = (n < HIDDEN) ? f2bf(w1[k * HIDDEN + n]) : (uint16_t)0;
    } else if (gtid < 114688) {               // w3_t [384][128]
      const int i = gtid - 65536;
      const int n = i >> 7, k = i & 127;
      w3_t[i] = (n < HIDDEN) ? f2bf(w3[k * HIDDEN + n]) : (uint16_t)0;
    } else if (gtid < 159744) {               // w2_t [128][352]
      const int i = gtid - 114688;
      const int n = i / HIDP, k = i - n * HIDP;
      w2_t[i] = (k < HIDDEN) ? f2bf(w2[k * 128 + n]) : (uint16_t)0;
    }
  }

  const int w = tid >> 6, l = tid & 63;
  const int lg = l >> 4, lm = l & 15;
  const int row0 = blockIdx.x * 64 + w * 16;
  const int col0 = blockIdx.y * 64;

  const uint16_t* Bp = B1t + (size_t)(col0 + lm) * 128 + lg * 8;
  short8 bA0 = *(const short8*)(Bp);
  short8 bA1 = *(const short8*)(Bp + 32);
  short8 bA2 = *(const short8*)(Bp + 64);
  short8 bA3 = *(const short8*)(Bp + 96);

  short8 af[4];
  const float* Af = Av + (size_t)(row0 + lm) * 128 + lg * 8;
#pragma unroll
  for (int ks = 0; ks < 4; ++ks) {
    const f32x4 a0 = *(const f32x4*)(Af + ks * 32);
    const f32x4 a1 = *(const f32x4*)(Af + ks * 32 + 4);
    union { uint32_t u[4]; short8 s8; } cv;
    cv.u[0] = pk2(a0[0], a0[1]); cv.u[1] = pk2(a0[2], a0[3]);
    cv.u[2] = pk2(a1[0], a1[1]); cv.u[3] = pk2(a1[2], a1[3]);
    af[ks] = cv.s8;
  }

  f32x4 acc[4];
#pragma unroll
  for (int t = 0; t < 4; ++t) acc[t] = (f32x4){0.f, 0.f, 0.f, 0.f};

  short8 bB0 = *(const short8*)(Bp + 2048);
  short8 bB1 = *(const short8*)(Bp + 2048 + 32);
  short8 bB2 = *(const short8*)(Bp + 2048 + 64);
  short8 bB3 = *(const short8*)(Bp + 2048 + 96);
  acc[0] = mfma32(af[0], bA0, acc[0]);
  acc[0] = mfma32(af[1], bA1, acc[0]);
  acc[0] = mfma32(af[2], bA2, acc[0]);
  acc[0] = mfma32(af[3], bA3, acc[0]);
  bA0 = *(const short8*)(Bp + 4096);
  bA1 = *(const short8*)(Bp + 4096 + 32);
  bA2 = *(const short8*)(Bp + 4096 + 64);
  bA3 = *(const short8*)(Bp + 4096 + 96);
  acc[1] = mfma32(af[0], bB0, acc[1]);
  acc[1] = mfma32(af[1], bB1, acc[1]);
  acc[1] = mfma32(af[2], bB2, acc[1]);
  acc[1] = mfma32(af[3], bB3, acc[1]);
  bB0 = *(const short8*)(Bp + 6144);
  bB1 = *(const short8*)(Bp + 6144 + 32);
  bB2 = *(const short8*)(Bp + 6144 + 64);
  bB3 = *(const short8*)(Bp + 6144 + 96);
  acc[2] = mfma32(af[0], bA0, acc[2]);
  acc[2] = mfma32(af[1], bA1, acc[2]);
  acc[2] = mfma32(af[2], bA2, acc[2]);
  acc[2] = mfma32(af[3], bA3, acc[2]);
  acc[3] = mfma32(af[0], bB0, acc[3]);
  acc[3] = mfma32(af[1], bB1, acc[3]);
  acc[3] = mfma32(af[2], bB2, acc[3]);
  acc[3] = mfma32(af[3], bB3, acc[3]);

#pragma unroll
  for (int t = 0; t < 4; ++t) {
#pragma unroll
    for (int r = 0; r < 4; ++r) {
      const int row = row0 + lg * 4 + r;
      const int col = col0 + t * 16 + lm;
      const float v = acc[t][r];
      const int bb = row >> 11, ss = row & 2047;
      if (col < 128) {
        outb[(size_t)row * 128 + col] = f2bf(v);            // Q (pre-scaled)
      } else if (col < 256) {
        const int c = col - 128;
        kc_o[((size_t)((bb << 4) + (c >> 3)) * SEQ + ss) * 8 + (c & 7)] = f2bf(v);
      } else {
        const int c = col - 256;
        vt_o[((size_t)(bb * 128 + c)) * SEQ + ss] = f2bf(v);
      }
    }
  }
}

// ------------------------------------------------------------------
// Flash attention (r20): 8 q-tiles/wave, 4-way key-split, grid 1024
// (1 pass), SCALAR 1-fma exp2. No-max softmax; quarters merge via
// 32KB LDS. Do NOT tighten launch_bounds (r6/r7 lesson).
// ------------------------------------------------------------------
__global__ __launch_bounds__(256, 4) void attn_kernel(
    const uint16_t* __restrict__ qb,   // [MROWS][128]  (pre-scaled Q)
    const uint16_t* __restrict__ kc,   // [B*NH][SEQ][8]
    const uint16_t* __restrict__ vt,   // [B*NH*8][SEQ]
    uint16_t* __restrict__ attn_o)     // [MROWS][128]
{
  __shared__ __attribute__((aligned(16))) float part[4][64][32];

  const int tid = threadIdx.x;
  const int w = tid >> 6, l = tid & 63;
  const int lg = l >> 4, lm = l & 15;
  int bid = blockIdx.x;
  bid = (bid & 7) * 128 + (bid >> 3);   // bijective XCD swizzle (1024 % 8 == 0)
  const int qc = bid & 15;              // SEQ/128 = 16 q-chunks
  const int bh = bid >> 4;
  const int b = bh >> 4, h = bh & 15;
  const int q0 = qc * 128;
  const int kh = w;                     // key quarter per wave

  const short8 zero8 = {0, 0, 0, 0, 0, 0, 0, 0};
  const f32x4 zero4 = {0.f, 0.f, 0.f, 0.f};
  const short ob = (short)0x3F80;  // bf16 1.0
  const short8 ones8 = {ob, ob, ob, ob, ob, ob, ob, ob};

  short8 qf[8];
#pragma unroll
  for (int t = 0; t < 8; ++t) {
    qf[t] = zero8;
    if (lg == 0)
      qf[t] = *(const short8*)(qb + (size_t)(b * SEQ + q0 + t * 16 + lm) * DIM + h * HD);
  }

  const uint16_t* kp = kc + (size_t)bh * SEQ * HD +
                       (kh * 512 + 8 * (lm >> 2) + (lm & 3)) * HD;
  const uint16_t* vp = vt + (size_t)(bh * HD + (lm & 7)) * SEQ + kh * 512 + lg * 8;

  short8 k0 = zero8, k1 = zero8, k2 = zero8, k3 = zero8;
  short8 v0 = (lm == 8) ? ones8 : zero8;
  short8 v1 = v0;

  f32x4 acc[8];
#pragma unroll
  for (int t = 0; t < 8; ++t) acc[t] = zero4;

#define LK()                                       \
  do { if (lg == 0) {                              \
    k0 = *(const short8*)(kp);                     \
    k1 = *(const short8*)(kp + 32);                \
    k2 = *(const short8*)(kp + 256);               \
    k3 = *(const short8*)(kp + 288); }             \
    kp += 512; } while (0)

#define LV()                                       \
  do { if (lm < HD) {                              \
    v0 = *(const short8*)(vp);                     \
    v1 = *(const short8*)(vp + 32); }              \
    vp += 64; } while (0)

#define PACKP(SA, SB, OUT)                 \
  do { union { uint32_t u[4]; short8 s; } _t; \
    _t.u[0] = pke2(SA[0], SA[1]);          \
    _t.u[1] = pke2(SA[2], SA[3]);          \
    _t.u[2] = pke2(SB[0], SB[1]);          \
    _t.u[3] = pke2(SB[2], SB[3]);          \
    OUT = _t.s; } while (0)

  LK();
  LV();

#pragma unroll 1
  for (int it = 0; it < 8; ++it) {
#pragma unroll
    for (int t = 0; t < 8; ++t) {
      f32x4 s0 = mfma32(k0, qf[t], zero4);
      f32x4 s1 = mfma32(k1, qf[t], zero4);
      f32x4 s2 = mfma32(k2, qf[t], zero4);
      f32x4 s3 = mfma32(k3, qf[t], zero4);
      if (t == 7) LK();
      short8 p0, p1;
      PACKP(s0, s1, p0);
      PACKP(s2, s3, p1);
      acc[t] = mfma32(v0, p0, acc[t]);
      acc[t] = mfma32(v1, p1, acc[t]);
      if (t == 7) LV();
    }
  }

#undef LK
#undef LV
#undef PACKP

#pragma unroll
  for (int t = 0; t < 8; ++t) *(f32x4*)&part[w][l][t * 4] = acc[t];
  __syncthreads();

#pragma unroll
  for (int j = 0; j < 2; ++j) {
    const int tt = w * 2 + j;
    const f32x4 m = (*(const f32x4*)&part[0][l][tt * 4] +
                     *(const f32x4*)&part[1][l][tt * 4]) +
                    (*(const f32x4*)&part[2][l][tt * 4] +
                     *(const f32x4*)&part[3][l][tt * 4]);
    const float inv = 1.0f / __shfl(m[0], 32 + lm);
    if (lg < 2) {
      const size_t o = (size_t)(b * SEQ + q0 + tt * 16 + lm) * DIM + h * HD + lg * 4;
      *(uint32_t*)(attn_o + o)     = pk2(m[0] * inv, m[1] * inv);
      *(uint32_t*)(attn_o + o + 2) = pk2(m[2] * inv, m[3] * inv);
    }
  }
}

// ------------------------------------------------------------------
// Fused post-attention chain, 2 row-halves per wave (r21-proven).
// Block = 32 rows x 8 waves (512 thr); grid 256 = 1 block/CU.
// ------------------------------------------------------------------
__global__ __launch_bounds__(512, 2) void ffn_kernel(
    const uint16_t* __restrict__ attn_o,  // [MROWS][128] bf16
    const float* __restrict__ x,          // [MROWS][128] fp32
    const uint16_t* __restrict__ wo_t,    // [128][128]
    const uint16_t* __restrict__ w1_t,    // [384][128] (rows>=344 zero)
    const uint16_t* __restrict__ w3_t,    // [384][128]
    const uint16_t* __restrict__ w2_t,    // [128][352] (k>=344 zero)
    float* __restrict__ out)              // [MROWS][128] fp32
{
  __shared__ __attribute__((aligned(16))) uint16_t h_l[2][16][136];
  __shared__ __attribute__((aligned(16))) uint16_t u_l[2][16][360];

  const int tid = threadIdx.x;
  const int w = tid >> 6, l = tid & 63;
  const int lg = l >> 4, lm = l & 15;
  const int R0 = blockIdx.x * 32;

  short8 af0[4], af1[4], wof[4], b1a[4], b3a[4];
  {
    const uint16_t* Ap0 = attn_o + (size_t)(R0 + lm) * 128 + lg * 8;
    const uint16_t* Ap1 = attn_o + (size_t)(R0 + 16 + lm) * 128 + lg * 8;
    const uint16_t* Bp = wo_t + (size_t)(w * 16 + lm) * 128 + lg * 8;
    const uint16_t* B1p = w1_t + (size_t)(w * 16 + lm) * 128 + lg * 8;
    const uint16_t* B3p = w3_t + (size_t)(w * 16 + lm) * 128 + lg * 8;
#pragma unroll
    for (int ks = 0; ks < 4; ++ks) {
      af0[ks] = *(const short8*)(Ap0 + ks * 32);
      af1[ks] = *(const short8*)(Ap1 + ks * 32);
      wof[ks] = *(const short8*)(Bp + ks * 32);
      b1a[ks] = *(const short8*)(B1p + ks * 32);
      b3a[ks] = *(const short8*)(B3p + ks * 32);
    }
  }

  float h0reg[4], h1reg[4];
  {
    f32x4 p00 = (f32x4){0.f, 0.f, 0.f, 0.f};
    f32x4 p01 = (f32x4){0.f, 0.f, 0.f, 0.f};
    f32x4 p10 = (f32x4){0.f, 0.f, 0.f, 0.f};
    f32x4 p11 = (f32x4){0.f, 0.f, 0.f, 0.f};
    p00 = mfma32(af0[0], wof[0], p00);
    p10 = mfma32(af1[0], wof[0], p10);
    p01 = mfma32(af0[1], wof[1], p01);
    p11 = mfma32(af1[1], wof[1], p11);
    p00 = mfma32(af0[2], wof[2], p00);
    p10 = mfma32(af1[2], wof[2], p10);
    p01 = mfma32(af0[3], wof[3], p01);
    p11 = mfma32(af1[3], wof[3], p11);
    const f32x4 a0 = p00 + p01;
    const f32x4 a1 = p10 + p11;
#pragma unroll
    for (int r = 0; r < 4; ++r) {
      const float h0 = a0[r] + x[(size_t)(R0 + lg * 4 + r) * 128 + w * 16 + lm];
      const float h1 = a1[r] + x[(size_t)(R0 + 16 + lg * 4 + r) * 128 + w * 16 + lm];
      h0reg[r] = h0;
      h1reg[r] = h1;
      h_l[0][lg * 4 + r][w * 16 + lm] = f2bf(h0);
      h_l[1][lg * 4 + r][w * 16 + lm] = f2bf(h1);
    }
  }
  __syncthreads();

  short8 afh0[4], afh1[4];
#pragma unroll
  for (int ks = 0; ks < 4; ++ks) {
    afh0[ks] = *(const short8*)&h_l[0][lm][ks * 32 + lg * 8];
    afh1[ks] = *(const short8*)&h_l[1][lm][ks * 32 + lg * 8];
  }

#define BSTAGE(CT, PREFETCH_CT, DO_PREFETCH)                        \
  do {                                                              \
    f32x4 g0 = (f32x4){0.f, 0.f, 0.f, 0.f};                         \
    f32x4 e0 = (f32x4){0.f, 0.f, 0.f, 0.f};                         \
    f32x4 g1 = (f32x4){0.f, 0.f, 0.f, 0.f};                         \
    f32x4 e1 = (f32x4){0.f, 0.f, 0.f, 0.f};                         \
    _Pragma("unroll")                                               \
    for (int ks = 0; ks < 4; ++ks) {                                \
      g0 = mfma32(afh0[ks], b1a[ks], g0);                           \
      g1 = mfma32(afh1[ks], b1a[ks], g1);                           \
      e0 = mfma32(afh0[ks], b3a[ks], e0);                           \
      e1 = mfma32(afh1[ks], b3a[ks], e1);                           \
    }                                                               \
    if (DO_PREFETCH) {                                              \
      const uint16_t* B1p = w1_t + (size_t)((PREFETCH_CT) * 16 + lm) * 128 + lg * 8; \
      const uint16_t* B3p = w3_t + (size_t)((PREFETCH_CT) * 16 + lm) * 128 + lg * 8; \
      _Pragma("unroll")                                             \
      for (int ks = 0; ks < 4; ++ks) {                              \
        b1a[ks] = *(const short8*)(B1p + ks * 32);                  \
        b3a[ks] = *(const short8*)(B3p + ks * 32);                  \
      }                                                             \
    }                                                               \
    _Pragma("unroll")                                               \
    for (int r = 0; r < 4; ++r) {                                   \
      const float ga = g0[r];                                       \
      const float gb = g1[r];                                       \
      const float u0 = ga / (1.f + __expf(-ga)) * e0[r];            \
      const float u1 = gb / (1.f + __expf(-gb)) * e1[r];            \
      u_l[0][lg * 4 + r][(CT) * 16 + lm] = f2bf(u0);                \
      u_l[1][lg * 4 + r][(CT) * 16 + lm] = f2bf(u1);                \
    }                                                               \
  } while (0)

  BSTAGE(w, w + 8, 1);
  BSTAGE(w + 8, w + 16, (w < 6));
  if (w < 6) BSTAGE(w + 16, 0, 0);

#undef BSTAGE
  __syncthreads();

  {
    short8 w2f0, w2f1, w2f2, w2f3;
    const uint16_t* Bp = w2_t + (size_t)(w * 16 + lm) * HIDP + lg * 8;
    w2f0 = *(const short8*)(Bp);
    w2f1 = *(const short8*)(Bp + 32);
    w2f2 = *(const short8*)(Bp + 64);
    w2f3 = *(const short8*)(Bp + 96);
    f32x4 c0 = (f32x4){0.f, 0.f, 0.f, 0.f};
    f32x4 c1 = (f32x4){0.f, 0.f, 0.f, 0.f};
#define CSTEP(K2, WF, RELOAD_OFF, DO_RELOAD)                        \
    do {                                                            \
      const short8 u0 = *(const short8*)&u_l[0][lm][(K2) * 32 + lg * 8]; \
      const short8 u1 = *(const short8*)&u_l[1][lm][(K2) * 32 + lg * 8]; \
      c0 = mfma32(u0, WF, c0);                                      \
      c1 = mfma32(u1, WF, c1);                                      \
      if (DO_RELOAD) WF = *(const short8*)(Bp + (RELOAD_OFF));      \
    } while (0)
    CSTEP(0, w2f0, 128, 1);
    CSTEP(1, w2f1, 160, 1);
    CSTEP(2, w2f2, 192, 1);
    CSTEP(3, w2f3, 224, 1);
    CSTEP(4, w2f0, 256, 1);
    CSTEP(5, w2f1, 288, 1);
    CSTEP(6, w2f2, 320, 1);
    CSTEP(7, w2f3, 0, 0);
    CSTEP(8, w2f0, 0, 0);
    CSTEP(9, w2f1, 0, 0);
    CSTEP(10, w2f2, 0, 0);
#undef CSTEP
#pragma unroll
    for (int r = 0; r < 4; ++r) {
      out[(size_t)(R0 + lg * 4 + r) * 128 + w * 16 + lm] = h0reg[r] + c0[r];
      out[(size_t)(R0 + 16 + lg * 4 + r) * 128 + w * 16 + lm] = h1reg[r] + c1[r];
    }
  }
}

// ------------------------------------------------------------------
extern "C" void kernel_launch(void* const* d_in, const int* in_sizes, int n_in,
                              void* d_out, int out_size, void* d_ws, size_t ws_size,
                              hipStream_t stream) {
  const float* x  = (const float*)d_in[0];
  const float* wq = (const float*)d_in[1];
  const float* wk = (const float*)d_in[2];
  const float* wv = (const float*)d_in[3];
  const float* wo = (const float*)d_in[4];
  const float* w1 = (const float*)d_in[5];
  const float* w3 = (const float*)d_in[6];
  const float* w2 = (const float*)d_in[7];
  float* out = (float*)d_out;

  char* ws = (char*)d_ws;
  size_t off = 0;
  auto alloc = [&](size_t bytes) {
    size_t o = off;
    off += (bytes + 255) & ~(size_t)255;
    return o;
  };
  uint16_t* qkv_t  = (uint16_t*)(ws + alloc(384 * 128 * 2));
  uint16_t* wo_t   = (uint16_t*)(ws + alloc(128 * 128 * 2));
  uint16_t* w1_t   = (uint16_t*)(ws + alloc(384 * 128 * 2));
  uint16_t* w3_t   = (uint16_t*)(ws + alloc(384 * 128 * 2));
  uint16_t* w2_t   = (uint16_t*)(ws + alloc(128 * HIDP * 2));
  uint16_t* q_buf  = (uint16_t*)(ws + alloc((size_t)MROWS * DIM * 2));
  uint16_t* kc_b   = (uint16_t*)(ws + alloc((size_t)MROWS * DIM * 2));
  uint16_t* vt_b   = (uint16_t*)(ws + alloc((size_t)MROWS * DIM * 2));
  uint16_t* attn_o = (uint16_t*)(ws + alloc((size_t)MROWS * DIM * 2));

  // prep: only qkv_t (98K elements)
  prep_kernel<<<128, 256, 0, stream>>>(wq, wk, wv, qkv_t);
  // qkv = x @ [wq*log2e | wk | wv]; prologue converts FFN weights
  qkv_gemm<<<dim3(MROWS / 64, 6), 256, 0, stream>>>(
      x, qkv_t, q_buf, kc_b, vt_b,
      wo, w1, w3, w2, wo_t, w1_t, w3_t, w2_t);
  // flash attention: 1024 blocks (1 pass), 8 q-tiles/wave, scalar exp2
  attn_kernel<<<dim3(BATCH * NH * (SEQ / 128)), 256, 0, stream>>>(
      q_buf, kc_b, vt_b, attn_o);
  // fused: h = x + attn@wo; out = h + silu(h@w1)*(h@w3)@w2
  ffn_kernel<<<dim3(MROWS / 32), 512, 0, stream>>>(
      attn_o, x, wo_t, w1_t, w3_t, w2_t, out);
}

// Round 27
// 57.149 us; speedup vs baseline: 1.0169x; 1.0169x over previous
//
#include <hip/hip_runtime.h>
#include <hip/hip_bf16.h>
#include <stdint.h>
#include <math.h>

typedef __attribute__((ext_vector_type(8))) short short8;
typedef __attribute__((ext_vector_type(4))) float f32x4;

#define NTHREADS 256
#define DIM 128
#define NH 16
#define HD 8
#define HIDDEN 344
#define HIDP 352          // HIDDEN padded to multiple of 32 (22 col-tiles)
#define BATCH 4
#define SEQ 2048
#define MROWS (BATCH * SEQ)   // 8192
#define LOG2E 1.4426950408889634f

static __device__ __forceinline__ uint16_t f2bf(float f) {
  union { float f; uint32_t u; } v; v.f = f;
  uint32_t r = v.u + 0x7FFFu + ((v.u >> 16) & 1u);
  return (uint16_t)(r >> 16);
}
// RNE pack: compiler emits v_cvt_pk_bf16_f32
static __device__ __forceinline__ uint32_t pk2(float lo, float hi) {
  union { __hip_bfloat162 b; uint32_t u; } c;
  c.b = __float22bfloat162_rn(make_float2(lo, hi));
  return c.u;
}
// ---- 1-fma exp2 -> bf16 (Schraudolph + 1.5*2^23 magic-add) ----
// SCALAR FMA ONLY (r22 asm NaN; r24 compiler-packed 0.109 absmax).
#define MAGIC_BF 12599163.0f   // 1.5*2^23 + (127 - 0.0436)*2^7
static __device__ __forceinline__ uint32_t pke2(float a, float b) {
  const float ua = fmaf(a, 128.0f, MAGIC_BF);
  const float ub = fmaf(b, 128.0f, MAGIC_BF);
  return __builtin_amdgcn_perm(__builtin_bit_cast(uint32_t, ub),
                               __builtin_bit_cast(uint32_t, ua), 0x05040100u);
}
static __device__ __forceinline__ f32x4 mfma32(short8 a, short8 b, f32x4 c) {
  return __builtin_amdgcn_mfma_f32_16x16x32_bf16(a, b, c, 0, 0, 0);
}

// ------------------------------------------------------------------
// prep: weights -> transposed bf16 Wt[n][k], padded where needed.
// (r26 lesson: fusing this into qkv_gemm's prologue was net negative;
// the standalone launch overlaps in graph replay.)
// ------------------------------------------------------------------
__global__ __launch_bounds__(256) void prep_kernel(
    const float* __restrict__ wq,
    const float* __restrict__ wk, const float* __restrict__ wv,
    const float* __restrict__ wo, const float* __restrict__ w1,
    const float* __restrict__ w3, const float* __restrict__ w2,
    uint16_t* __restrict__ qkv_t,
    uint16_t* __restrict__ wo_t,  uint16_t* __restrict__ w1_t,
    uint16_t* __restrict__ w3_t,  uint16_t* __restrict__ w2_t)
{
  const int nt  = gridDim.x * blockDim.x;
  const int tid = blockIdx.x * blockDim.x + threadIdx.x;
  for (int i = tid; i < 384 * 128; i += nt) {
    int n = i >> 7, k = i & 127;
    const float* w = (n < 128) ? wq : ((n < 256) ? wk : wv);
    const float s = (n < 128) ? LOG2E : 1.0f;
    qkv_t[i] = f2bf(w[k * 128 + (n & 127)] * s);
  }
  for (int i = tid; i < 128 * 128; i += nt) {
    int n = i >> 7, k = i & 127;
    wo_t[i] = f2bf(wo[k * 128 + n]);
  }
  for (int i = tid; i < 384 * 128; i += nt) {
    int n = i >> 7, k = i & 127;
    w1_t[i] = (n < HIDDEN) ? f2bf(w1[k * HIDDEN + n]) : (uint16_t)0;
    w3_t[i] = (n < HIDDEN) ? f2bf(w3[k * HIDDEN + n]) : (uint16_t)0;
  }
  for (int i = tid; i < 128 * HIDP; i += nt) {
    int n = i / HIDP, k = i - n * HIDP;
    w2_t[i] = (k < HIDDEN) ? f2bf(w2[k * 128 + n]) : (uint16_t)0;
  }
}

// ------------------------------------------------------------------
// Register-streaming QKV GEMM with B-frag software pipeline (r19).
// 768 blocks = 4/CU occupancy.
// ------------------------------------------------------------------
__global__ __launch_bounds__(256, 4) void qkv_gemm(
    const float* __restrict__ Av, const uint16_t* __restrict__ B1t,
    uint16_t* __restrict__ outb,
    uint16_t* __restrict__ kc_o, uint16_t* __restrict__ vt_o)
{
  const int tid = threadIdx.x;
  const int w = tid >> 6, l = tid & 63;
  const int lg = l >> 4, lm = l & 15;
  const int row0 = blockIdx.x * 64 + w * 16;
  const int col0 = blockIdx.y * 64;

  const uint16_t* Bp = B1t + (size_t)(col0 + lm) * 128 + lg * 8;
  short8 bA0 = *(const short8*)(Bp);
  short8 bA1 = *(const short8*)(Bp + 32);
  short8 bA2 = *(const short8*)(Bp + 64);
  short8 bA3 = *(const short8*)(Bp + 96);

  short8 af[4];
  const float* Af = Av + (size_t)(row0 + lm) * 128 + lg * 8;
#pragma unroll
  for (int ks = 0; ks < 4; ++ks) {
    const f32x4 a0 = *(const f32x4*)(Af + ks * 32);
    const f32x4 a1 = *(const f32x4*)(Af + ks * 32 + 4);
    union { uint32_t u[4]; short8 s8; } cv;
    cv.u[0] = pk2(a0[0], a0[1]); cv.u[1] = pk2(a0[2], a0[3]);
    cv.u[2] = pk2(a1[0], a1[1]); cv.u[3] = pk2(a1[2], a1[3]);
    af[ks] = cv.s8;
  }

  f32x4 acc[4];
#pragma unroll
  for (int t = 0; t < 4; ++t) acc[t] = (f32x4){0.f, 0.f, 0.f, 0.f};

  short8 bB0 = *(const short8*)(Bp + 2048);
  short8 bB1 = *(const short8*)(Bp + 2048 + 32);
  short8 bB2 = *(const short8*)(Bp + 2048 + 64);
  short8 bB3 = *(const short8*)(Bp + 2048 + 96);
  acc[0] = mfma32(af[0], bA0, acc[0]);
  acc[0] = mfma32(af[1], bA1, acc[0]);
  acc[0] = mfma32(af[2], bA2, acc[0]);
  acc[0] = mfma32(af[3], bA3, acc[0]);
  bA0 = *(const short8*)(Bp + 4096);
  bA1 = *(const short8*)(Bp + 4096 + 32);
  bA2 = *(const short8*)(Bp + 4096 + 64);
  bA3 = *(const short8*)(Bp + 4096 + 96);
  acc[1] = mfma32(af[0], bB0, acc[1]);
  acc[1] = mfma32(af[1], bB1, acc[1]);
  acc[1] = mfma32(af[2], bB2, acc[1]);
  acc[1] = mfma32(af[3], bB3, acc[1]);
  bB0 = *(const short8*)(Bp + 6144);
  bB1 = *(const short8*)(Bp + 6144 + 32);
  bB2 = *(const short8*)(Bp + 6144 + 64);
  bB3 = *(const short8*)(Bp + 6144 + 96);
  acc[2] = mfma32(af[0], bA0, acc[2]);
  acc[2] = mfma32(af[1], bA1, acc[2]);
  acc[2] = mfma32(af[2], bA2, acc[2]);
  acc[2] = mfma32(af[3], bA3, acc[2]);
  acc[3] = mfma32(af[0], bB0, acc[3]);
  acc[3] = mfma32(af[1], bB1, acc[3]);
  acc[3] = mfma32(af[2], bB2, acc[3]);
  acc[3] = mfma32(af[3], bB3, acc[3]);

#pragma unroll
  for (int t = 0; t < 4; ++t) {
#pragma unroll
    for (int r = 0; r < 4; ++r) {
      const int row = row0 + lg * 4 + r;
      const int col = col0 + t * 16 + lm;
      const float v = acc[t][r];
      const int bb = row >> 11, ss = row & 2047;
      if (col < 128) {
        outb[(size_t)row * 128 + col] = f2bf(v);            // Q (pre-scaled)
      } else if (col < 256) {
        const int c = col - 128;
        kc_o[((size_t)((bb << 4) + (c >> 3)) * SEQ + ss) * 8 + (c & 7)] = f2bf(v);
      } else {
        const int c = col - 256;
        vt_o[((size_t)(bb * 128 + c)) * SEQ + ss] = f2bf(v);
      }
    }
  }
}

// ------------------------------------------------------------------
// Flash attention (r20): 8 q-tiles/wave, 4-way key-split, grid 1024
// (1 pass), SCALAR 1-fma exp2. No-max softmax; quarters merge via
// 32KB LDS. Do NOT tighten launch_bounds (r6/r7 lesson).
// ------------------------------------------------------------------
__global__ __launch_bounds__(256, 4) void attn_kernel(
    const uint16_t* __restrict__ qb,   // [MROWS][128]  (pre-scaled Q)
    const uint16_t* __restrict__ kc,   // [B*NH][SEQ][8]
    const uint16_t* __restrict__ vt,   // [B*NH*8][SEQ]
    uint16_t* __restrict__ attn_o)     // [MROWS][128]
{
  __shared__ __attribute__((aligned(16))) float part[4][64][32];

  const int tid = threadIdx.x;
  const int w = tid >> 6, l = tid & 63;
  const int lg = l >> 4, lm = l & 15;
  int bid = blockIdx.x;
  bid = (bid & 7) * 128 + (bid >> 3);   // bijective XCD swizzle (1024 % 8 == 0)
  const int qc = bid & 15;              // SEQ/128 = 16 q-chunks
  const int bh = bid >> 4;
  const int b = bh >> 4, h = bh & 15;
  const int q0 = qc * 128;
  const int kh = w;                     // key quarter per wave

  const short8 zero8 = {0, 0, 0, 0, 0, 0, 0, 0};
  const f32x4 zero4 = {0.f, 0.f, 0.f, 0.f};
  const short ob = (short)0x3F80;  // bf16 1.0
  const short8 ones8 = {ob, ob, ob, ob, ob, ob, ob, ob};

  short8 qf[8];
#pragma unroll
  for (int t = 0; t < 8; ++t) {
    qf[t] = zero8;
    if (lg == 0)
      qf[t] = *(const short8*)(qb + (size_t)(b * SEQ + q0 + t * 16 + lm) * DIM + h * HD);
  }

  const uint16_t* kp = kc + (size_t)bh * SEQ * HD +
                       (kh * 512 + 8 * (lm >> 2) + (lm & 3)) * HD;
  const uint16_t* vp = vt + (size_t)(bh * HD + (lm & 7)) * SEQ + kh * 512 + lg * 8;

  short8 k0 = zero8, k1 = zero8, k2 = zero8, k3 = zero8;
  short8 v0 = (lm == 8) ? ones8 : zero8;
  short8 v1 = v0;

  f32x4 acc[8];
#pragma unroll
  for (int t = 0; t < 8; ++t) acc[t] = zero4;

#define LK()                                       \
  do { if (lg == 0) {                              \
    k0 = *(const short8*)(kp);                     \
    k1 = *(const short8*)(kp + 32);                \
    k2 = *(const short8*)(kp + 256);               \
    k3 = *(const short8*)(kp + 288); }             \
    kp += 512; } while (0)

#define LV()                                       \
  do { if (lm < HD) {                              \
    v0 = *(const short8*)(vp);                     \
    v1 = *(const short8*)(vp + 32); }              \
    vp += 64; } while (0)

#define PACKP(SA, SB, OUT)                 \
  do { union { uint32_t u[4]; short8 s; } _t; \
    _t.u[0] = pke2(SA[0], SA[1]);          \
    _t.u[1] = pke2(SA[2], SA[3]);          \
    _t.u[2] = pke2(SB[0], SB[1]);          \
    _t.u[3] = pke2(SB[2], SB[3]);          \
    OUT = _t.s; } while (0)

  LK();
  LV();

#pragma unroll 1
  for (int it = 0; it < 8; ++it) {
#pragma unroll
    for (int t = 0; t < 8; ++t) {
      f32x4 s0 = mfma32(k0, qf[t], zero4);
      f32x4 s1 = mfma32(k1, qf[t], zero4);
      f32x4 s2 = mfma32(k2, qf[t], zero4);
      f32x4 s3 = mfma32(k3, qf[t], zero4);
      if (t == 7) LK();
      short8 p0, p1;
      PACKP(s0, s1, p0);
      PACKP(s2, s3, p1);
      acc[t] = mfma32(v0, p0, acc[t]);
      acc[t] = mfma32(v1, p1, acc[t]);
      if (t == 7) LV();
    }
  }

#undef LK
#undef LV
#undef PACKP

#pragma unroll
  for (int t = 0; t < 8; ++t) *(f32x4*)&part[w][l][t * 4] = acc[t];
  __syncthreads();

#pragma unroll
  for (int j = 0; j < 2; ++j) {
    const int tt = w * 2 + j;
    const f32x4 m = (*(const f32x4*)&part[0][l][tt * 4] +
                     *(const f32x4*)&part[1][l][tt * 4]) +
                    (*(const f32x4*)&part[2][l][tt * 4] +
                     *(const f32x4*)&part[3][l][tt * 4]);
    const float inv = 1.0f / __shfl(m[0], 32 + lm);
    if (lg < 2) {
      const size_t o = (size_t)(b * SEQ + q0 + tt * 16 + lm) * DIM + h * HD + lg * 4;
      *(uint32_t*)(attn_o + o)     = pk2(m[0] * inv, m[1] * inv);
      *(uint32_t*)(attn_o + o + 2) = pk2(m[2] * inv, m[3] * inv);
    }
  }
}

// ------------------------------------------------------------------
// Fused post-attention chain, 2 row-halves per wave (r21-proven).
// Block = 32 rows x 8 waves (512 thr); grid 256 = 1 block/CU.
// ------------------------------------------------------------------
__global__ __launch_bounds__(512, 2) void ffn_kernel(
    const uint16_t* __restrict__ attn_o,  // [MROWS][128] bf16
    const float* __restrict__ x,          // [MROWS][128] fp32
    const uint16_t* __restrict__ wo_t,    // [128][128]
    const uint16_t* __restrict__ w1_t,    // [384][128] (rows>=344 zero)
    const uint16_t* __restrict__ w3_t,    // [384][128]
    const uint16_t* __restrict__ w2_t,    // [128][352] (k>=344 zero)
    float* __restrict__ out)              // [MROWS][128] fp32
{
  __shared__ __attribute__((aligned(16))) uint16_t h_l[2][16][136];
  __shared__ __attribute__((aligned(16))) uint16_t u_l[2][16][360];

  const int tid = threadIdx.x;
  const int w = tid >> 6, l = tid & 63;
  const int lg = l >> 4, lm = l & 15;
  const int R0 = blockIdx.x * 32;

  short8 af0[4], af1[4], wof[4], b1a[4], b3a[4];
  {
    const uint16_t* Ap0 = attn_o + (size_t)(R0 + lm) * 128 + lg * 8;
    const uint16_t* Ap1 = attn_o + (size_t)(R0 + 16 + lm) * 128 + lg * 8;
    const uint16_t* Bp = wo_t + (size_t)(w * 16 + lm) * 128 + lg * 8;
    const uint16_t* B1p = w1_t + (size_t)(w * 16 + lm) * 128 + lg * 8;
    const uint16_t* B3p = w3_t + (size_t)(w * 16 + lm) * 128 + lg * 8;
#pragma unroll
    for (int ks = 0; ks < 4; ++ks) {
      af0[ks] = *(const short8*)(Ap0 + ks * 32);
      af1[ks] = *(const short8*)(Ap1 + ks * 32);
      wof[ks] = *(const short8*)(Bp + ks * 32);
      b1a[ks] = *(const short8*)(B1p + ks * 32);
      b3a[ks] = *(const short8*)(B3p + ks * 32);
    }
  }

  float h0reg[4], h1reg[4];
  {
    f32x4 p00 = (f32x4){0.f, 0.f, 0.f, 0.f};
    f32x4 p01 = (f32x4){0.f, 0.f, 0.f, 0.f};
    f32x4 p10 = (f32x4){0.f, 0.f, 0.f, 0.f};
    f32x4 p11 = (f32x4){0.f, 0.f, 0.f, 0.f};
    p00 = mfma32(af0[0], wof[0], p00);
    p10 = mfma32(af1[0], wof[0], p10);
    p01 = mfma32(af0[1], wof[1], p01);
    p11 = mfma32(af1[1], wof[1], p11);
    p00 = mfma32(af0[2], wof[2], p00);
    p10 = mfma32(af1[2], wof[2], p10);
    p01 = mfma32(af0[3], wof[3], p01);
    p11 = mfma32(af1[3], wof[3], p11);
    const f32x4 a0 = p00 + p01;
    const f32x4 a1 = p10 + p11;
#pragma unroll
    for (int r = 0; r < 4; ++r) {
      const float h0 = a0[r] + x[(size_t)(R0 + lg * 4 + r) * 128 + w * 16 + lm];
      const float h1 = a1[r] + x[(size_t)(R0 + 16 + lg * 4 + r) * 128 + w * 16 + lm];
      h0reg[r] = h0;
      h1reg[r] = h1;
      h_l[0][lg * 4 + r][w * 16 + lm] = f2bf(h0);
      h_l[1][lg * 4 + r][w * 16 + lm] = f2bf(h1);
    }
  }
  __syncthreads();

  short8 afh0[4], afh1[4];
#pragma unroll
  for (int ks = 0; ks < 4; ++ks) {
    afh0[ks] = *(const short8*)&h_l[0][lm][ks * 32 + lg * 8];
    afh1[ks] = *(const short8*)&h_l[1][lm][ks * 32 + lg * 8];
  }

#define BSTAGE(CT, PREFETCH_CT, DO_PREFETCH)                        \
  do {                                                              \
    f32x4 g0 = (f32x4){0.f, 0.f, 0.f, 0.f};                         \
    f32x4 e0 = (f32x4){0.f, 0.f, 0.f, 0.f};                         \
    f32x4 g1 = (f32x4){0.f, 0.f, 0.f, 0.f};                         \
    f32x4 e1 = (f32x4){0.f, 0.f, 0.f, 0.f};                         \
    _Pragma("unroll")                                               \
    for (int ks = 0; ks < 4; ++ks) {                                \
      g0 = mfma32(afh0[ks], b1a[ks], g0);                           \
      g1 = mfma32(afh1[ks], b1a[ks], g1);                           \
      e0 = mfma32(afh0[ks], b3a[ks], e0);                           \
      e1 = mfma32(afh1[ks], b3a[ks], e1);                           \
    }                                                               \
    if (DO_PREFETCH) {                                              \
      const uint16_t* B1p = w1_t + (size_t)((PREFETCH_CT) * 16 + lm) * 128 + lg * 8; \
      const uint16_t* B3p = w3_t + (size_t)((PREFETCH_CT) * 16 + lm) * 128 + lg * 8; \
      _Pragma("unroll")                                             \
      for (int ks = 0; ks < 4; ++ks) {                              \
        b1a[ks] = *(const short8*)(B1p + ks * 32);                  \
        b3a[ks] = *(const short8*)(B3p + ks * 32);                  \
      }                                                             \
    }                                                               \
    _Pragma("unroll")                                               \
    for (int r = 0; r < 4; ++r) {                                   \
      const float ga = g0[r];                                       \
      const float gb = g1[r];                                       \
      const float u0 = ga / (1.f + __expf(-ga)) * e0[r];            \
      const float u1 = gb / (1.f + __expf(-gb)) * e1[r];            \
      u_l[0][lg * 4 + r][(CT) * 16 + lm] = f2bf(u0);                \
      u_l[1][lg * 4 + r][(CT) * 16 + lm] = f2bf(u1);                \
    }                                                               \
  } while (0)

  BSTAGE(w, w + 8, 1);
  BSTAGE(w + 8, w + 16, (w < 6));
  if (w < 6) BSTAGE(w + 16, 0, 0);

#undef BSTAGE
  __syncthreads();

  {
    short8 w2f0, w2f1, w2f2, w2f3;
    const uint16_t* Bp = w2_t + (size_t)(w * 16 + lm) * HIDP + lg * 8;
    w2f0 = *(const short8*)(Bp);
    w2f1 = *(const short8*)(Bp + 32);
    w2f2 = *(const short8*)(Bp + 64);
    w2f3 = *(const short8*)(Bp + 96);
    f32x4 c0 = (f32x4){0.f, 0.f, 0.f, 0.f};
    f32x4 c1 = (f32x4){0.f, 0.f, 0.f, 0.f};
#define CSTEP(K2, WF, RELOAD_OFF, DO_RELOAD)                        \
    do {                                                            \
      const short8 u0 = *(const short8*)&u_l[0][lm][(K2) * 32 + lg * 8]; \
      const short8 u1 = *(const short8*)&u_l[1][lm][(K2) * 32 + lg * 8]; \
      c0 = mfma32(u0, WF, c0);                                      \
      c1 = mfma32(u1, WF, c1);                                      \
      if (DO_RELOAD) WF = *(const short8*)(Bp + (RELOAD_OFF));      \
    } while (0)
    CSTEP(0, w2f0, 128, 1);
    CSTEP(1, w2f1, 160, 1);
    CSTEP(2, w2f2, 192, 1);
    CSTEP(3, w2f3, 224, 1);
    CSTEP(4, w2f0, 256, 1);
    CSTEP(5, w2f1, 288, 1);
    CSTEP(6, w2f2, 320, 1);
    CSTEP(7, w2f3, 0, 0);
    CSTEP(8, w2f0, 0, 0);
    CSTEP(9, w2f1, 0, 0);
    CSTEP(10, w2f2, 0, 0);
#undef CSTEP
#pragma unroll
    for (int r = 0; r < 4; ++r) {
      out[(size_t)(R0 + lg * 4 + r) * 128 + w * 16 + lm] = h0reg[r] + c0[r];
      out[(size_t)(R0 + 16 + lg * 4 + r) * 128 + w * 16 + lm] = h1reg[r] + c1[r];
    }
  }
}

// ------------------------------------------------------------------
extern "C" void kernel_launch(void* const* d_in, const int* in_sizes, int n_in,
                              void* d_out, int out_size, void* d_ws, size_t ws_size,
                              hipStream_t stream) {
  const float* x  = (const float*)d_in[0];
  const float* wq = (const float*)d_in[1];
  const float* wk = (const float*)d_in[2];
  const float* wv = (const float*)d_in[3];
  const float* wo = (const float*)d_in[4];
  const float* w1 = (const float*)d_in[5];
  const float* w3 = (const float*)d_in[6];
  const float* w2 = (const float*)d_in[7];
  float* out = (float*)d_out;

  char* ws = (char*)d_ws;
  size_t off = 0;
  auto alloc = [&](size_t bytes) {
    size_t o = off;
    off += (bytes + 255) & ~(size_t)255;
    return o;
  };
  uint16_t* qkv_t  = (uint16_t*)(ws + alloc(384 * 128 * 2));
  uint16_t* wo_t   = (uint16_t*)(ws + alloc(128 * 128 * 2));
  uint16_t* w1_t   = (uint16_t*)(ws + alloc(384 * 128 * 2));
  uint16_t* w3_t   = (uint16_t*)(ws + alloc(384 * 128 * 2));
  uint16_t* w2_t   = (uint16_t*)(ws + alloc(128 * HIDP * 2));
  uint16_t* q_buf  = (uint16_t*)(ws + alloc((size_t)MROWS * DIM * 2));
  uint16_t* kc_b   = (uint16_t*)(ws + alloc((size_t)MROWS * DIM * 2));
  uint16_t* vt_b   = (uint16_t*)(ws + alloc((size_t)MROWS * DIM * 2));
  uint16_t* attn_o = (uint16_t*)(ws + alloc((size_t)MROWS * DIM * 2));

  prep_kernel<<<512, 256, 0, stream>>>(wq, wk, wv, wo, w1, w3, w2,
                                       qkv_t, wo_t, w1_t, w3_t, w2_t);
  // qkv = x @ [wq*log2e | wk | wv]; 768 blocks (r19 pipeline)
  qkv_gemm<<<dim3(MROWS / 64, 6), 256, 0, stream>>>(
      x, qkv_t, q_buf, kc_b, vt_b);
  // flash attention: 1024 blocks (1 pass), 8 q-tiles/wave, scalar exp2
  attn_kernel<<<dim3(BATCH * NH * (SEQ / 128)), 256, 0, stream>>>(
      q_buf, kc_b, vt_b, attn_o);
  // fused: h = x + attn@wo; out = h + silu(h@w1)*(h@w3)@w2
  ffn_kernel<<<dim3(MROWS / 32), 512, 0, stream>>>(
      attn_o, x, wo_t, w1_t, w3_t, w2_t, out);
}